// Round 4
// baseline (237.415 us; speedup 1.0000x reference)
//
#include <hip/hip_runtime.h>
#include <hip/hip_cooperative_groups.h>

namespace cg = cooperative_groups;

// NonlocalWeightedAverage, v3: single cooperative kernel.
// Phase 1: convert feature rows to fragment-order bf16 (+ row sum-of-squares).
// Phase 2: iterate feature rows r; row r contributes (dy=2,1,0) to the three
// in-flight corr accumulators my = r-1, r, r+1. Fixed-max softmax
// (M[q] = 10 * 3x3 box-sum of ssq; diagonal dominance => exact one-hot).

#define NPIX 4096
#define ROWCH 528              // 8 kchunks * 66 xslots (xslot 0,65 zero pad)
#define ROWB  (ROWCH * 16)     // 8448 B
#define SCALE 10.0f

typedef __attribute__((ext_vector_type(8))) short bf16x8;
typedef __attribute__((ext_vector_type(4))) float f32x4;

__device__ __forceinline__ void gld16(const uint4* g, char* l) {
    __builtin_amdgcn_global_load_lds(
        (const __attribute__((address_space(1))) unsigned int*)g,
        (__attribute__((address_space(3))) unsigned int*)l, 16, 0, 0);
}

#define MF(a, b, c) __builtin_amdgcn_mfma_f32_16x16x32_bf16(a, b, c, 0, 0, 0)

// 12 MFMAs: target slot S, base d-index D (= dy*3), AF idx d*4 + ks*2 + ti
#define MFMA_T(S, D) do {                                                     \
    acc[S][0] = MF(AF[(D) * 4 + 0],  B00, acc[S][0]);                         \
    acc[S][1] = MF(AF[(D) * 4 + 1],  B00, acc[S][1]);                         \
    acc[S][0] = MF(AF[(D) * 4 + 4],  B01, acc[S][0]);                         \
    acc[S][1] = MF(AF[(D) * 4 + 5],  B01, acc[S][1]);                         \
    acc[S][0] = MF(AF[(D) * 4 + 8],  B02, acc[S][0]);                         \
    acc[S][1] = MF(AF[(D) * 4 + 9],  B02, acc[S][1]);                         \
    acc[S][0] = MF(AF[(D) * 4 + 2],  B10, acc[S][0]);                         \
    acc[S][1] = MF(AF[(D) * 4 + 3],  B10, acc[S][1]);                         \
    acc[S][0] = MF(AF[(D) * 4 + 6],  B11, acc[S][0]);                         \
    acc[S][1] = MF(AF[(D) * 4 + 7],  B11, acc[S][1]);                         \
    acc[S][0] = MF(AF[(D) * 4 + 10], B12, acc[S][0]);                         \
    acc[S][1] = MF(AF[(D) * 4 + 11], B12, acc[S][1]);                         \
} while (0)

#define RETIRE(S, myv) do {                                                   \
    const float* xr = xlb + (myv) * 64 + kx;                                  \
    const float xv0 = xr[0], xv1 = xr[NPIX], xv2 = xr[2 * NPIX];              \
    _Pragma("unroll")                                                         \
    for (int ti2 = 0; ti2 < 2; ++ti2) {                                       \
        _Pragma("unroll")                                                     \
        for (int rg = 0; rg < 4; ++rg) {                                      \
            const int s2 = ti2 * 4 + rg;                                      \
            const float e = __expf(fmaf(acc[S][ti2][rg], SCALE, negM[s2]));   \
            l_[s2] += e;                                                      \
            A0[s2] = fmaf(e, xv0, A0[s2]);                                    \
            A1[s2] = fmaf(e, xv1, A1[s2]);                                    \
            A2[s2] = fmaf(e, xv2, A2[s2]);                                    \
        }                                                                     \
        acc[S][ti2] = (f32x4){0.f, 0.f, 0.f, 0.f};                            \
    }                                                                         \
} while (0)

// SN = (RM+1)%3, SR = (RM+2)%3; B-ring slot RM, prefetch into slot SR.
#define STEP(RM, SN, SR, rr) do {                                             \
    const int r_ = (rr);                                                      \
    if (r_ + 2 < 64) {                                                        \
        const uint4* src = fT + (size_t)(r_ + 2) * ROWCH + w * 66;            \
        char* dst = smem + (SR) * ROWB + w * 1056;                            \
        gld16(src + lane, dst + lane * 16);                                   \
        if (lane < 2) gld16(src + 64 + lane, dst + 1024 + lane * 16);         \
    }                                                                         \
    if (r_ < 64) {                                                            \
        const char* base = smem + (RM) * ROWB + bu;                           \
        const bf16x8 B00 = *(const bf16x8*)(base);                            \
        const bf16x8 B01 = *(const bf16x8*)(base + 16);                       \
        const bf16x8 B02 = *(const bf16x8*)(base + 32);                       \
        const bf16x8 B10 = *(const bf16x8*)(base + 4224);                     \
        const bf16x8 B11 = *(const bf16x8*)(base + 4240);                     \
        const bf16x8 B12 = *(const bf16x8*)(base + 4256);                     \
        if (r_ >= 1)     MFMA_T(SR, 6);   /* my=r-1, dy=2 */                  \
        MFMA_T(RM, 3);                    /* my=r,   dy=1 */                  \
        if (r_ + 1 < 64) MFMA_T(SN, 0);   /* my=r+1, dy=0 */                  \
    }                                                                         \
    if (r_ >= 1) RETIRE(SR, r_ - 1);                                          \
    if (r_ < 64) __syncthreads();                                             \
} while (0)

__global__ __launch_bounds__(512, 2) void nlwa_fused(
    const float* __restrict__ x_lab, const float* __restrict__ feature,
    float* __restrict__ out, uint4* __restrict__ fTg, float* __restrict__ gsq)
{
    __shared__ __align__(16) char smem[3 * ROWB];   // 25344 B

    const int tid = threadIdx.x;
    const int bid = blockIdx.x;
    const int b = bid >> 6, ny = bid & 63;

    // ================= phase 1: this block converts feature row (b, y=ny) ===
    {
        const int kc = tid >> 6, x = tid & 63;
        const float* fb = feature + ((size_t)b * 64 + kc * 8) * NPIX + ny * 64 + x;
        float ss = 0.f;
        unsigned h[8];
#pragma unroll
        for (int j = 0; j < 8; ++j) {
            const float f = fb[(size_t)j * NPIX];
            ss = fmaf(f, f, ss);
            unsigned u = __float_as_uint(f);
            u = u + 0x7fffu + ((u >> 16) & 1u);   // RNE to bf16
            h[j] = u >> 16;
        }
        uint4 pk;
        pk.x = h[0] | (h[1] << 16); pk.y = h[2] | (h[3] << 16);
        pk.z = h[4] | (h[5] << 16); pk.w = h[6] | (h[7] << 16);
        fTg[(size_t)bid * ROWCH + kc * 66 + x + 1] = pk;
        if (tid < 16)
            fTg[(size_t)bid * ROWCH + (tid >> 1) * 66 + (tid & 1) * 65] =
                (uint4){0u, 0u, 0u, 0u};
        float* scr1 = (float*)smem;
        scr1[kc * 64 + x] = ss;
        __syncthreads();
        if (tid < 64) {
            float s = 0.f;
#pragma unroll
            for (int k = 0; k < 8; ++k) s += scr1[k * 64 + tid];
            gsq[bid * 64 + tid] = s;
        }
    }
    __threadfence();
    cg::this_grid().sync();

    // ================= phase 2 =================
    const int w = tid >> 6, lane = tid & 63;
    const int quad = lane >> 4, nl = lane & 15;
    const int qhalf = w & 1, kq = w >> 1;
    const int qofs = qhalf * 32;
    const uint4* fT = fTg + (size_t)b * (64 * ROWCH);
    const float* xlb = x_lab + (size_t)b * 3 * NPIX;
    const int kx = kq * 16 + nl;
    const int bu = (quad * 66 + nl + kq * 16) * 16;

    // ring init: rows 0,1 -> slots 0,1 (contiguous copy)
    for (int i = tid; i < 2 * ROWCH; i += 512)
        ((uint4*)smem)[i] = fT[i];

    // A fragments (36 = 9 d x 2 ks x 2 qtiles), from global -> registers
    bf16x8 AF[36];
    {
        const bf16x8 zf = {0, 0, 0, 0, 0, 0, 0, 0};
#pragma unroll
        for (int d = 0; d < 9; ++d) {
            const int dyi = d / 3, dx = d - dyi * 3;
            const int qr = ny + dyi - 1;
            const bool ok = (qr >= 0) && (qr < 64);
            const uint4* rowp = fT + (size_t)(ok ? qr : 0) * ROWCH;
#pragma unroll
            for (int ks = 0; ks < 2; ++ks)
#pragma unroll
                for (int ti = 0; ti < 2; ++ti) {
                    const int unit = (quad + ks * 4) * 66 +
                                     (qofs + ti * 16 + nl + dx);
                    const bf16x8 f = *(const bf16x8*)(rowp + unit);
                    AF[d * 4 + ks * 2 + ti] = ok ? f : zf;
                }
        }
    }

    // fixed softmax offsets: M[q] = SCALE * 3x3 box-sum of gsq
    float negM[8];
    {
        const float* gb = gsq + b * NPIX;
#pragma unroll
        for (int s = 0; s < 8; ++s) {
            const int q = qofs + (s >> 2) * 16 + quad * 4 + (s & 3);
            float a = 0.f;
#pragma unroll
            for (int dy = -1; dy <= 1; ++dy) {
                const int ry = ny + dy;
#pragma unroll
                for (int dx = -1; dx <= 1; ++dx) {
                    const int rx = q + dx;
                    const bool v = (ry >= 0) && (ry < 64) && (rx >= 0) && (rx < 64);
                    a += v ? gb[ry * 64 + rx] : 0.f;
                }
            }
            negM[s] = -SCALE * a;
        }
    }

    float l_[8], A0[8], A1[8], A2[8];
#pragma unroll
    for (int s = 0; s < 8; ++s) { l_[s] = 0.f; A0[s] = 0.f; A1[s] = 0.f; A2[s] = 0.f; }
    f32x4 acc[3][2];
#pragma unroll
    for (int i = 0; i < 3; ++i) {
        acc[i][0] = (f32x4){0.f, 0.f, 0.f, 0.f};
        acc[i][1] = (f32x4){0.f, 0.f, 0.f, 0.f};
    }

    __syncthreads();

    for (int rb = 0; rb < 66; rb += 3) {
        STEP(0, 1, 2, rb);
        STEP(1, 2, 0, rb + 1);
        STEP(2, 0, 1, rb + 2);
    }

    // ---- combine: reduce over nl (16 key cols) in-wave, then over 4 kq ----
#pragma unroll
    for (int s = 0; s < 8; ++s) {
#pragma unroll
        for (int off = 8; off >= 1; off >>= 1) {
            l_[s] += __shfl_down(l_[s], off, 16);
            A0[s] += __shfl_down(A0[s], off, 16);
            A1[s] += __shfl_down(A1[s], off, 16);
            A2[s] += __shfl_down(A2[s], off, 16);
        }
    }
    float4* scr = (float4*)smem;   // [64 q][4 kq] = 4 KB
    if (nl == 0) {
#pragma unroll
        for (int s = 0; s < 8; ++s) {
            const int q = qofs + (s >> 2) * 16 + quad * 4 + (s & 3);
            scr[q * 4 + kq] = make_float4(l_[s], A0[s], A1[s], A2[s]);
        }
    }
    __syncthreads();
    if (tid < 64) {
        const float4 t0 = scr[tid * 4 + 0], t1 = scr[tid * 4 + 1];
        const float4 t2 = scr[tid * 4 + 2], t3 = scr[tid * 4 + 3];
        const float inv = 1.0f / (t0.x + t1.x + t2.x + t3.x);
        float* o = out + (size_t)b * 3 * NPIX + ny * 64 + tid;
        o[0]        = (t0.y + t1.y + t2.y + t3.y) * inv;
        o[NPIX]     = (t0.z + t1.z + t2.z + t3.z) * inv;
        o[2 * NPIX] = (t0.w + t1.w + t2.w + t3.w) * inv;
    }
}

extern "C" void kernel_launch(void* const* d_in, const int* in_sizes, int n_in,
                              void* d_out, int out_size, void* d_ws, size_t ws_size,
                              hipStream_t stream) {
    (void)in_sizes; (void)n_in; (void)out_size; (void)ws_size;
    const float* x_lab   = (const float*)d_in[0];
    const float* feature = (const float*)d_in[1];
    float* out = (float*)d_out;
    uint4* fTg = (uint4*)d_ws;                                   // 2,162,688 B
    float* gsq = (float*)((char*)d_ws + (size_t)256 * ROWB);     // 65,536 B
    void* args[] = {(void*)&x_lab, (void*)&feature, (void*)&out,
                    (void*)&fTg, (void*)&gsq};
    hipLaunchCooperativeKernel((void*)nlwa_fused, dim3(256), dim3(512),
                               args, 0, stream);
}

// Round 5
// 134.359 us; speedup vs baseline: 1.7670x; 1.7670x over previous
//
#include <hip/hip_runtime.h>

// NonlocalWeightedAverage v4: single plain kernel, fully fused.
// Per block (b, ny): convert q rows + stream key rows fp32->bf16 through a
// 3-slot LDS ring; 9-shift MFMA (16x16x32 bf16) with dy-reuse (each feature
// row read once, feeding my = r-1, r, r+1); fixed-max softmax via negM.
// Waves: 4 q-quarters x 2 k-halves => AF = 18 frags (72 VGPRs).

#define NPIX 4096
#define ROWCH 528              // 8 kchunks * 66 xslots (xslot 0,65 zero pad)
#define ROWB  (ROWCH * 16)     // 8448 B
#define SCALE 10.0f

typedef __attribute__((ext_vector_type(8))) short bf16x8;
typedef __attribute__((ext_vector_type(4))) float f32x4;

#define MF(a, b, c) __builtin_amdgcn_mfma_f32_16x16x32_bf16(a, b, c, 0, 0, 0)

__device__ __forceinline__ uint4 pack8(const float* v) {
    unsigned h[8];
#pragma unroll
    for (int j = 0; j < 8; ++j) {
        unsigned u = __float_as_uint(v[j]);
        u = u + 0x7fffu + ((u >> 16) & 1u);   // RNE to bf16
        h[j] = u >> 16;
    }
    return (uint4){h[0] | (h[1] << 16), h[2] | (h[3] << 16),
                   h[4] | (h[5] << 16), h[6] | (h[7] << 16)};
}

__device__ __forceinline__ void load_row(const float* fr, int kc, int x, float* L) {
#pragma unroll
    for (int j = 0; j < 8; ++j) L[j] = fr[(size_t)(kc * 8 + j) * NPIX + x];
}

// 12 MFMAs into target slot T with AF base index DBASE (= q-side dy * 3)
#define MFMA_GRP(T, DBASE) do {                                               \
    _Pragma("unroll")                                                         \
    for (int dx = 0; dx < 3; ++dx)                                            \
        _Pragma("unroll")                                                     \
        for (int ks = 0; ks < 2; ++ks) {                                      \
            acc[T][0] = MF(AF[((DBASE) + dx) * 2 + ks], Bf[ks][0][dx], acc[T][0]); \
            acc[T][1] = MF(AF[((DBASE) + dx) * 2 + ks], Bf[ks][1][dx], acc[T][1]); \
        }                                                                     \
} while (0)

#define RETIRE(S, myv) do {                                                   \
    _Pragma("unroll")                                                         \
    for (int kt = 0; kt < 2; ++kt) {                                          \
        const int kx = kh * 32 + kt * 16 + nl;                                \
        const float xv0 = xls[(myv) * 64 + kx];                               \
        const float xv1 = xls[NPIX + (myv) * 64 + kx];                        \
        const float xv2 = xls[2 * NPIX + (myv) * 64 + kx];                    \
        _Pragma("unroll")                                                     \
        for (int rg = 0; rg < 4; ++rg) {                                      \
            const float e = __expf(fmaf(acc[S][kt][rg], SCALE, negM[rg]));    \
            l_[rg] += e;                                                      \
            A0[rg] = fmaf(e, xv0, A0[rg]);                                    \
            A1[rg] = fmaf(e, xv1, A1[rg]);                                    \
            A2[rg] = fmaf(e, xv2, A2[rg]);                                    \
        }                                                                     \
        acc[S][kt] = (f32x4){0.f, 0.f, 0.f, 0.f};                             \
    }                                                                         \
} while (0)

// Ring slots: read RM (= r%3); write row r+2 into SR (=(r+2)%3); SN=(r+1)%3.
#define STEP(RM, SN, SR, rr) do {                                             \
    const int r_ = (rr);                                                      \
    if (r_ <= 61) *(uint4*)(ring + (SR) * ROWB + wu16) = pack8(L);            \
    if (r_ <= 60) load_row(featb + (r_ + 3) * 64, kc, x, L);                  \
    if (r_ < 64) {                                                            \
        const char* base = ring + (RM) * ROWB + bu;                           \
        bf16x8 Bf[2][2][3];                                                   \
        _Pragma("unroll")                                                     \
        for (int ks = 0; ks < 2; ++ks)                                        \
            _Pragma("unroll")                                                 \
            for (int kt = 0; kt < 2; ++kt) {                                  \
                const char* p = base + (ks * 264 + kt * 16) * 16;             \
                Bf[ks][kt][0] = *(const bf16x8*)(p);                          \
                Bf[ks][kt][1] = *(const bf16x8*)(p + 16);                     \
                Bf[ks][kt][2] = *(const bf16x8*)(p + 32);                     \
            }                                                                 \
        if (r_ >= 1)     MFMA_GRP(SR, 6);   /* my=r-1, dy=2 (final) */        \
        MFMA_GRP(RM, 3);                    /* my=r,   dy=1 */                \
        if (r_ + 1 < 64) MFMA_GRP(SN, 0);   /* my=r+1, dy=0 */                \
    }                                                                         \
    if (r_ >= 1 && r_ <= 64) RETIRE(SR, r_ - 1);                              \
    if (r_ < 64) __syncthreads();                                             \
} while (0)

__global__ __launch_bounds__(512)
__attribute__((amdgpu_waves_per_eu(2, 2)))
void nlwa_fused(const float* __restrict__ x_lab,
                const float* __restrict__ feature,
                float* __restrict__ out)
{
    __shared__ __align__(16) char ring[3 * ROWB];   // 25344 B
    __shared__ float xls[3 * NPIX];                 // 49152 B
    __shared__ float part[3][8][64];                // 6144 B
    __shared__ float ssq[3][64];                    // 768 B
    __shared__ float4 scrF[64][2];                  // 2048 B

    const int tid = threadIdx.x;
    const int b = blockIdx.x >> 6, ny = blockIdx.x & 63;
    const int w = tid >> 6, lane = tid & 63;
    const int quad = lane >> 4, nl = lane & 15;
    const int qw = w & 3, kh = w >> 2;              // q quarter, key half
    const int kc = w, x = lane;                     // staging unit (kchunk, col)
    const int wu16 = (kc * 66 + x + 1) * 16;        // this thread's ds_write slot
    const int bu = (quad * 66 + kh * 32 + nl) * 16; // B fragment lane base

    const float* featb = feature + (size_t)b * 64 * NPIX;
    const float* xb = x_lab + (size_t)b * 3 * NPIX;

    // ---- stage x_lab[b] (48 KB) into LDS ----
    {
        const float4* s4 = (const float4*)xb;
        float4* d4 = (float4*)xls;
        for (int i = tid; i < 3 * NPIX / 4; i += 512) d4[i] = s4[i];
    }
    // ---- zero the pad units of all 3 ring slots ----
    if (tid < 48) {
        const int sl = tid / 16, pu = tid % 16;
        const int u = (pu >> 1) * 66 + (pu & 1) * 65;
        *(uint4*)(ring + sl * ROWB + u * 16) = (uint4){0u, 0u, 0u, 0u};
    }

    // ---- convert the 3 query rows into ring slots; ssq partials ----
    float L[8];
#pragma unroll
    for (int dyi = 0; dyi < 3; ++dyi) {
        const int qr = ny + dyi - 1;
        float ss = 0.f;
        if (qr >= 0 && qr < 64) {
            load_row(featb + qr * 64, kc, x, L);
#pragma unroll
            for (int j = 0; j < 8; ++j) ss = fmaf(L[j], L[j], ss);
            *(uint4*)(ring + dyi * ROWB + wu16) = pack8(L);
        } else {
            *(uint4*)(ring + dyi * ROWB + wu16) = (uint4){0u, 0u, 0u, 0u};
        }
        part[dyi][kc][x] = ss;
    }
    __syncthreads();

    if (tid < 192) {
        const int dyi = tid >> 6, xx = tid & 63;
        float s = 0.f;
#pragma unroll
        for (int k = 0; k < 8; ++k) s += part[dyi][k][xx];
        ssq[dyi][xx] = s;
    }

    // ---- A fragments: 18 = 9 (dy,dx) x 2 ks, for this wave's 16 queries ----
    bf16x8 AF[18];
#pragma unroll
    for (int dyi = 0; dyi < 3; ++dyi)
#pragma unroll
        for (int dx = 0; dx < 3; ++dx)
#pragma unroll
            for (int ks = 0; ks < 2; ++ks)
                AF[(dyi * 3 + dx) * 2 + ks] = *(const bf16x8*)(ring + dyi * ROWB +
                    ((quad + ks * 4) * 66 + qw * 16 + nl + dx) * 16);
    __syncthreads();   // ssq ready; AF reads drained before ring overwrite

    // ---- fixed softmax offsets ----
    float negM[4];
#pragma unroll
    for (int rg = 0; rg < 4; ++rg) {
        const int q = qw * 16 + quad * 4 + rg;
        float a = 0.f;
#pragma unroll
        for (int dyi = 0; dyi < 3; ++dyi)
#pragma unroll
            for (int dx = -1; dx <= 1; ++dx) {
                const int cx = q + dx;
                a += (cx >= 0 && cx < 64) ? ssq[dyi][cx] : 0.f;
            }
        negM[rg] = -SCALE * a;
    }

    // ---- stage key rows 0,1 into slots 0,1; preload row 2 into L ----
#pragma unroll
    for (int rr = 0; rr < 2; ++rr) {
        load_row(featb + rr * 64, kc, x, L);
        *(uint4*)(ring + rr * ROWB + wu16) = pack8(L);
    }
    load_row(featb + 2 * 64, kc, x, L);

    float l_[4], A0[4], A1[4], A2[4];
#pragma unroll
    for (int rg = 0; rg < 4; ++rg) { l_[rg] = 0.f; A0[rg] = 0.f; A1[rg] = 0.f; A2[rg] = 0.f; }
    f32x4 acc[3][2];
#pragma unroll
    for (int i = 0; i < 3; ++i) {
        acc[i][0] = (f32x4){0.f, 0.f, 0.f, 0.f};
        acc[i][1] = (f32x4){0.f, 0.f, 0.f, 0.f};
    }
    __syncthreads();

    for (int rb = 0; rb < 66; rb += 3) {
        STEP(0, 1, 2, rb);
        STEP(1, 2, 0, rb + 1);
        STEP(2, 0, 1, rb + 2);
    }

    // ---- combine: shfl-reduce 16 key cols, LDS-reduce 2 key halves ----
#pragma unroll
    for (int rg = 0; rg < 4; ++rg) {
#pragma unroll
        for (int off = 8; off >= 1; off >>= 1) {
            l_[rg] += __shfl_down(l_[rg], off, 16);
            A0[rg] += __shfl_down(A0[rg], off, 16);
            A1[rg] += __shfl_down(A1[rg], off, 16);
            A2[rg] += __shfl_down(A2[rg], off, 16);
        }
    }
    if (nl == 0) {
#pragma unroll
        for (int rg = 0; rg < 4; ++rg) {
            const int q = qw * 16 + quad * 4 + rg;
            scrF[q][kh] = make_float4(l_[rg], A0[rg], A1[rg], A2[rg]);
        }
    }
    __syncthreads();
    if (tid < 64) {
        const float4 t0 = scrF[tid][0], t1 = scrF[tid][1];
        const float inv = 1.0f / (t0.x + t1.x);
        float* o = out + (size_t)b * 3 * NPIX + ny * 64 + tid;
        o[0]        = (t0.y + t1.y) * inv;
        o[NPIX]     = (t0.z + t1.z) * inv;
        o[2 * NPIX] = (t0.w + t1.w) * inv;
    }
}

extern "C" void kernel_launch(void* const* d_in, const int* in_sizes, int n_in,
                              void* d_out, int out_size, void* d_ws, size_t ws_size,
                              hipStream_t stream) {
    (void)in_sizes; (void)n_in; (void)out_size; (void)d_ws; (void)ws_size;
    const float* x_lab   = (const float*)d_in[0];
    const float* feature = (const float*)d_in[1];
    float* out = (float*)d_out;
    nlwa_fused<<<dim3(256), dim3(512), 0, stream>>>(x_lab, feature, out);
}